// Round 1
// baseline (106.295 us; speedup 1.0000x reference)
//
#include <hip/hip_runtime.h>

#define B_   32
#define H_   16
#define L_   577
#define D_   1024
#define CK   64
#define LP   576    // L-1 patches
#define DOM  54
#define NSEL 55     // DOM + CLS
#define NR   522    // LP - DOM
#define CTX  10
#define NMERGE 512  // NR - CTX

// remain-list position for merge index m: p = m + min(m/51,9) + 1
__device__ __forceinline__ int remain_pos(int m) {
    int k = m / 51; if (k > 9) k = 9;
    return m + k + 1;
}

// block-wide sum over 576 threads (9 waves)
__device__ float block_sum576(float v) {
    __shared__ float red[9];
    __shared__ float tot;
    for (int o = 32; o; o >>= 1) v += __shfl_xor(v, o);
    if ((threadIdx.x & 63) == 0) red[threadIdx.x >> 6] = v;
    __syncthreads();
    if (threadIdx.x < 16) {
        float s = (threadIdx.x < 9) ? red[threadIdx.x] : 0.f;
        for (int o = 8; o; o >>= 1) s += __shfl_xor(s, o);
        if (threadIdx.x == 0) tot = s;
    }
    __syncthreads();
    float r = tot;
    __syncthreads();   // safe reuse of red/tot on next call
    return r;
}

// K1: score + z-score + top-54 selection + index lists
__global__ __launch_bounds__(576) void k_score(
    const float* __restrict__ attn, const float* __restrict__ metric,
    const float* __restrict__ text, int* __restrict__ dom_idx,
    int* __restrict__ rem_tok)
{
    const int b = blockIdx.x;
    const int j = threadIdx.x;       // patch index 0..575, token j+1

    __shared__ float tsh[CK];
    __shared__ float inv_tn;
    __shared__ float sc[LP];
    __shared__ int   sel[LP];

    if (threadIdx.x < CK) {
        float t = text[b * CK + threadIdx.x];
        tsh[threadIdx.x] = t;
        float s = t * t;
        for (int o = 32; o; o >>= 1) s += __shfl_xor(s, o);
        if (threadIdx.x == 0) inv_tn = 1.f / (sqrtf(s) + 1e-12f);
    }
    __syncthreads();

    // Sd: sum over heads of attn[b,h,0,1+j]
    float Sd = 0.f;
    {
        size_t base = (size_t)b * H_ * L_ * L_ + (size_t)(1 + j);
        #pragma unroll
        for (int h = 0; h < H_; ++h)
            Sd += attn[base + (size_t)h * L_ * L_];
    }

    // cos score: normalized metric[b,1+j] . normalized text
    float cosv;
    {
        const float4* row = (const float4*)&metric[((size_t)(b * L_ + 1 + j)) * CK];
        float dot = 0.f, ss = 0.f;
        #pragma unroll
        for (int c4 = 0; c4 < CK / 4; ++c4) {
            float4 v = row[c4];
            ss  += v.x * v.x + v.y * v.y + v.z * v.z + v.w * v.w;
            dot += v.x * tsh[c4*4+0] + v.y * tsh[c4*4+1] +
                   v.z * tsh[c4*4+2] + v.w * tsh[c4*4+3];
        }
        cosv = dot / (sqrtf(ss) + 1e-12f) * inv_tn;
    }

    // z-scores (ddof=1, eps added to std)
    float mS = block_sum576(Sd)   * (1.f / LP);
    float dS = Sd - mS;
    float vS = block_sum576(dS * dS) * (1.f / (LP - 1));
    float mC = block_sum576(cosv) * (1.f / LP);
    float dC = cosv - mC;
    float vC = block_sum576(dC * dC) * (1.f / (LP - 1));

    float score = 0.5f * dS / (sqrtf(vS) + 1e-6f) + 0.5f * dC / (sqrtf(vC) + 1e-6f);
    sc[j] = score;
    __syncthreads();

    // rank with stable tie-break (score desc, index asc) — exact top_k reproduction
    int rank = 0;
    for (int k = 0; k < LP; ++k) {
        float s = sc[k];
        rank += (s > score) || (s == score && k < j);
    }
    sel[j] = (rank < DOM) ? 1 : 0;
    __syncthreads();

    int pre = 0;   // # selected patches with index < j
    for (int k = 0; k < LP; ++k) pre += sel[k] & (k < j ? 1 : 0);

    if (j == 0) dom_idx[b * NSEL] = 0;
    if (sel[j]) dom_idx[b * NSEL + 1 + pre] = j + 1;
    else        rem_tok[b * NR + (j - pre)] = j + 1;
}

// K2: normalize metric rows of remaining tokens (1 wave per token)
__global__ __launch_bounds__(256) void k_norm(
    const float* __restrict__ metric, const int* __restrict__ rem_tok,
    float* __restrict__ metric_n)
{
    int t = blockIdx.x * 4 + (threadIdx.x >> 6);
    int lane = threadIdx.x & 63;
    if (t >= B_ * NR) return;
    int b = t / NR, p = t - b * NR;
    int tok = rem_tok[b * NR + p];
    float v = metric[((size_t)(b * L_ + tok)) * CK + lane];
    float s = v * v;
    for (int o = 32; o; o >>= 1) s += __shfl_xor(s, o);
    metric_n[(size_t)t * CK + lane] = v / (sqrtf(s) + 1e-12f);
}

// K3: argmax-cosine assignment of 512 merge tokens to 10 targets + counts
__global__ __launch_bounds__(512) void k_assign(
    const float* __restrict__ metric_n, int* __restrict__ assign,
    float* __restrict__ counts)
{
    const int b = blockIdx.x;
    const int tid = threadIdx.x;
    __shared__ float tg[CTX * CK];
    __shared__ int scount[CTX];

    if (tid < CTX) scount[tid] = 0;
    for (int i = tid; i < CTX * CK; i += 512) {
        int k = i >> 6, c = i & 63;
        tg[i] = metric_n[((size_t)(b * NR + 52 * k)) * CK + c];
    }
    __syncthreads();

    int p = remain_pos(tid);
    const float4* row = (const float4*)&metric_n[((size_t)(b * NR + p)) * CK];
    float4 r[CK / 4];
    #pragma unroll
    for (int c4 = 0; c4 < CK / 4; ++c4) r[c4] = row[c4];

    float best = -1e30f; int bk = 0;
    #pragma unroll
    for (int k = 0; k < CTX; ++k) {
        float d = 0.f;
        #pragma unroll
        for (int c4 = 0; c4 < CK / 4; ++c4) {
            float4 v = r[c4];
            d += v.x * tg[k*CK + c4*4+0] + v.y * tg[k*CK + c4*4+1] +
                 v.z * tg[k*CK + c4*4+2] + v.w * tg[k*CK + c4*4+3];
        }
        if (d > best) { best = d; bk = k; }   // strict > : first max, like jnp.argmax
    }
    assign[b * NMERGE + tid] = bk;
    atomicAdd(&scount[bk], 1);
    __syncthreads();
    if (tid < CTX) counts[b * CTX + tid] = fmaxf((float)scount[tid], 1.0f);
}

// K4: gather dominant rows + aggregate contextual rows
__global__ __launch_bounds__(256) void k_out(
    const float* __restrict__ hidden, const int* __restrict__ dom_idx,
    const int* __restrict__ rem_tok, const int* __restrict__ assign,
    const float* __restrict__ counts, float* __restrict__ out)
{
    const int b = blockIdx.x / 65, r = blockIdx.x % 65;
    const int tid = threadIdx.x;
    float4* dst = (float4*)&out[((size_t)(b * 65 + r)) * D_];

    if (r < NSEL) {
        int tok = dom_idx[b * NSEL + r];
        const float4* src = (const float4*)&hidden[((size_t)(b * L_ + tok)) * D_];
        dst[tid] = src[tid];
    } else {
        const int k = r - NSEL;
        __shared__ int toks[NMERGE];
        for (int i = tid; i < NMERGE; i += 256) {
            int a = assign[b * NMERGE + i];
            toks[i] = (a == k) ? rem_tok[b * NR + remain_pos(i)] : -1;
        }
        __syncthreads();

        float4 acc = make_float4(0.f, 0.f, 0.f, 0.f);
        for (int m = 0; m < NMERGE; ++m) {          // ascending m: deterministic
            int tok = toks[m];
            if (tok >= 0) {                          // block-uniform branch
                float4 v = ((const float4*)&hidden[((size_t)(b * L_ + tok)) * D_])[tid];
                acc.x += v.x; acc.y += v.y; acc.z += v.z; acc.w += v.w;
            }
        }
        int tgt_tok = rem_tok[b * NR + 52 * k];
        float4 bv = ((const float4*)&hidden[((size_t)(b * L_ + tgt_tok)) * D_])[tid];
        float inv = 1.0f / counts[b * CTX + k];
        float4 o;
        o.x = bv.x + acc.x * inv; o.y = bv.y + acc.y * inv;
        o.z = bv.z + acc.z * inv; o.w = bv.w + acc.w * inv;
        dst[tid] = o;
    }
}

extern "C" void kernel_launch(void* const* d_in, const int* in_sizes, int n_in,
                              void* d_out, int out_size, void* d_ws, size_t ws_size,
                              hipStream_t stream) {
    const float* attn   = (const float*)d_in[0];
    const float* hidden = (const float*)d_in[1];
    const float* metric = (const float*)d_in[2];
    const float* text   = (const float*)d_in[3];
    float* out = (float*)d_out;

    // workspace layout (256B aligned)
    char* ws = (char*)d_ws;
    size_t off = 0;
    auto alloc = [&](size_t bytes) { void* p = ws + off; off = (off + bytes + 255) & ~(size_t)255; return p; };
    int*   dom_idx  = (int*)  alloc((size_t)B_ * NSEL * 4);
    int*   rem_tok  = (int*)  alloc((size_t)B_ * NR * 4);
    int*   assign   = (int*)  alloc((size_t)B_ * NMERGE * 4);
    float* counts   = (float*)alloc((size_t)B_ * CTX * 4);
    float* metric_n = (float*)alloc((size_t)B_ * NR * CK * 4);

    k_score <<<B_, LP, 0, stream>>>(attn, metric, text, dom_idx, rem_tok);
    k_norm  <<<(B_ * NR) / 4, 256, 0, stream>>>(metric, rem_tok, metric_n);
    k_assign<<<B_, NMERGE, 0, stream>>>(metric_n, assign, counts);
    k_out   <<<B_ * 65, 256, 0, stream>>>(hidden, dom_idx, rem_tok, assign, counts, out);
}

// Round 2
// 60.091 us; speedup vs baseline: 1.7689x; 1.7689x over previous
//
#include <hip/hip_runtime.h>

#define B_   32
#define H_   16
#define L_   577
#define D_   1024
#define CK   64
#define LP   576    // L-1 patches
#define DOM  54
#define NSEL 55     // DOM + CLS
#define NR   522    // LP - DOM
#define CTX  10
#define NMERGE 512  // NR - CTX

// remain-list position for merge index m: p = m + min(m/51,9) + 1
__device__ __forceinline__ int remain_pos(int m) {
    int k = m / 51; if (k > 9) k = 9;
    return m + k + 1;
}

// block-wide sum over 576 threads (9 waves)
__device__ float block_sum576(float v) {
    __shared__ float red[9];
    __shared__ float tot;
    for (int o = 32; o; o >>= 1) v += __shfl_xor(v, o);
    if ((threadIdx.x & 63) == 0) red[threadIdx.x >> 6] = v;
    __syncthreads();
    if (threadIdx.x < 16) {
        float s = (threadIdx.x < 9) ? red[threadIdx.x] : 0.f;
        for (int o = 8; o; o >>= 1) s += __shfl_xor(s, o);
        if (threadIdx.x == 0) tot = s;
    }
    __syncthreads();
    float r = tot;
    __syncthreads();
    return r;
}

// K1: score + z-score + top-54 selection + index lists
__global__ __launch_bounds__(576) void k_score(
    const float* __restrict__ attn, const float* __restrict__ metric,
    const float* __restrict__ text, int* __restrict__ dom_idx,
    int* __restrict__ rem_tok)
{
    const int b = blockIdx.x;
    const int j = threadIdx.x;       // patch index 0..575, token j+1

    __shared__ float tsh[CK];
    __shared__ float inv_tn;
    __shared__ float sc[LP];
    __shared__ unsigned long long smask[9];

    if (threadIdx.x < CK) {
        float t = text[b * CK + threadIdx.x];
        tsh[threadIdx.x] = t;
        float s = t * t;
        for (int o = 32; o; o >>= 1) s += __shfl_xor(s, o);
        if (threadIdx.x == 0) inv_tn = 1.f / (sqrtf(s) + 1e-12f);
    }
    __syncthreads();

    // Sd: sum over heads of attn[b,h,0,1+j]
    float Sd = 0.f;
    {
        size_t base = (size_t)b * H_ * L_ * L_ + (size_t)(1 + j);
        #pragma unroll
        for (int h = 0; h < H_; ++h)
            Sd += attn[base + (size_t)h * L_ * L_];
    }

    // cos score: normalized metric[b,1+j] . normalized text
    float cosv;
    {
        const float4* row = (const float4*)&metric[((size_t)(b * L_ + 1 + j)) * CK];
        float dot = 0.f, ss = 0.f;
        #pragma unroll
        for (int c4 = 0; c4 < CK / 4; ++c4) {
            float4 v = row[c4];
            ss  += v.x * v.x + v.y * v.y + v.z * v.z + v.w * v.w;
            dot += v.x * tsh[c4*4+0] + v.y * tsh[c4*4+1] +
                   v.z * tsh[c4*4+2] + v.w * tsh[c4*4+3];
        }
        cosv = dot / (sqrtf(ss) + 1e-12f) * inv_tn;
    }

    // z-scores (ddof=1, eps added to std)
    float mS = block_sum576(Sd)   * (1.f / LP);
    float dS = Sd - mS;
    float vS = block_sum576(dS * dS) * (1.f / (LP - 1));
    float mC = block_sum576(cosv) * (1.f / LP);
    float dC = cosv - mC;
    float vC = block_sum576(dC * dC) * (1.f / (LP - 1));

    float score = 0.5f * dS / (sqrtf(vS) + 1e-6f) + 0.5f * dC / (sqrtf(vC) + 1e-6f);
    sc[j] = score;
    __syncthreads();

    // rank with stable tie-break (score desc, index asc) — exact top_k reproduction
    int rank = 0;
    for (int k = 0; k < LP; ++k) {
        float s = sc[k];
        rank += (s > score) || (s == score && k < j);
    }
    bool selj = (rank < DOM);

    // ballot-based stable prefix (# selected with index < j)
    const int w = j >> 6, lane = j & 63;
    unsigned long long m = __ballot(selj);
    if (lane == 0) smask[w] = m;
    __syncthreads();
    int pre = 0;
    for (int ww = 0; ww < w; ++ww) pre += __popcll(smask[ww]);
    pre += __popcll(smask[w] & ((1ull << lane) - 1ull));

    if (j == 0) dom_idx[b * NSEL] = 0;
    if (selj) dom_idx[b * NSEL + 1 + pre] = j + 1;
    else      rem_tok[b * NR + (j - pre)] = j + 1;
}

// K2: argmax-cosine assignment + deterministic compacted bucket lists.
// NOTE: merge-row normalization is dropped — argmax_k (m.t_k/|t_k|) is
// invariant to the positive factor 1/|m|.
__global__ __launch_bounds__(512) void k_assign(
    const float* __restrict__ metric, const int* __restrict__ rem_tok,
    int* __restrict__ bucket_toks, int* __restrict__ bucket_cnt)
{
    const int b = blockIdx.x;
    const int tid = threadIdx.x;
    __shared__ float tg[CTX * CK];
    __shared__ float tinv[CTX];
    __shared__ unsigned long long bmask[8][CTX];

    // stage 10 raw target rows
    for (int i = tid; i < CTX * CK; i += 512) {
        int k = i >> 6, c = i & 63;
        int tok = rem_tok[b * NR + 52 * k];
        tg[i] = metric[((size_t)(b * L_ + tok)) * CK + c];
    }
    __syncthreads();
    if (tid < CTX) {
        float s = 0.f;
        for (int c = 0; c < CK; ++c) { float t = tg[tid * CK + c]; s += t * t; }
        tinv[tid] = 1.f / (sqrtf(s) + 1e-12f);
    }
    __syncthreads();

    const int p = remain_pos(tid);
    const int tok = rem_tok[b * NR + p];
    const float4* row = (const float4*)&metric[((size_t)(b * L_ + tok)) * CK];
    float4 r[CK / 4];
    #pragma unroll
    for (int c4 = 0; c4 < CK / 4; ++c4) r[c4] = row[c4];

    float best = -1e30f; int bk = 0;
    #pragma unroll
    for (int k = 0; k < CTX; ++k) {
        float d = 0.f;
        #pragma unroll
        for (int c4 = 0; c4 < CK / 4; ++c4) {
            float4 v = r[c4];
            d += v.x * tg[k*CK + c4*4+0] + v.y * tg[k*CK + c4*4+1] +
                 v.z * tg[k*CK + c4*4+2] + v.w * tg[k*CK + c4*4+3];
        }
        d *= tinv[k];
        if (d > best) { best = d; bk = k; }   // strict > : first max, like jnp.argmax
    }

    // stable compaction: pos = #{i < tid : assign_i == bk} via ballots
    const int w = tid >> 6, lane = tid & 63;
    #pragma unroll
    for (int k = 0; k < CTX; ++k) {
        unsigned long long mk = __ballot(bk == k);
        if (lane == 0) bmask[w][k] = mk;
    }
    __syncthreads();
    int pos = 0;
    for (int ww = 0; ww < w; ++ww) pos += __popcll(bmask[ww][bk]);
    pos += __popcll(bmask[w][bk] & ((1ull << lane) - 1ull));
    bucket_toks[((size_t)(b * CTX + bk)) * NMERGE + pos] = tok;

    if (tid < CTX) {
        int c = 0;
        #pragma unroll
        for (int ww = 0; ww < 8; ++ww) c += __popcll(bmask[ww][tid]);
        bucket_cnt[b * CTX + tid] = c;
    }
}

// K3: gather dominant rows + aggregate contextual rows (compacted lists, ILP x4)
__global__ __launch_bounds__(256) void k_out(
    const float* __restrict__ hidden, const int* __restrict__ dom_idx,
    const int* __restrict__ rem_tok, const int* __restrict__ bucket_toks,
    const int* __restrict__ bucket_cnt, float* __restrict__ out)
{
    const int b = blockIdx.x / 65, r = blockIdx.x % 65;
    const int tid = threadIdx.x;
    float4* dst = (float4*)&out[((size_t)(b * 65 + r)) * D_];

    if (r < NSEL) {
        int tok = dom_idx[b * NSEL + r];
        const float4* src = (const float4*)&hidden[((size_t)(b * L_ + tok)) * D_];
        dst[tid] = src[tid];
    } else {
        const int k = r - NSEL;
        const int cnt = bucket_cnt[b * CTX + k];
        __shared__ int toks[NMERGE];
        for (int i = tid; i < cnt; i += 256)
            toks[i] = bucket_toks[((size_t)(b * CTX + k)) * NMERGE + i];
        __syncthreads();

        const float4* hb = (const float4*)&hidden[((size_t)b * L_) * D_];
        float4 a0 = make_float4(0,0,0,0), a1 = a0, a2 = a0, a3 = a0;
        int i = 0;
        for (; i + 4 <= cnt; i += 4) {
            float4 v0 = hb[(size_t)toks[i+0] * 256 + tid];
            float4 v1 = hb[(size_t)toks[i+1] * 256 + tid];
            float4 v2 = hb[(size_t)toks[i+2] * 256 + tid];
            float4 v3 = hb[(size_t)toks[i+3] * 256 + tid];
            a0.x += v0.x; a0.y += v0.y; a0.z += v0.z; a0.w += v0.w;
            a1.x += v1.x; a1.y += v1.y; a1.z += v1.z; a1.w += v1.w;
            a2.x += v2.x; a2.y += v2.y; a2.z += v2.z; a2.w += v2.w;
            a3.x += v3.x; a3.y += v3.y; a3.z += v3.z; a3.w += v3.w;
        }
        for (; i < cnt; ++i) {
            float4 v = hb[(size_t)toks[i] * 256 + tid];
            a0.x += v.x; a0.y += v.y; a0.z += v.z; a0.w += v.w;
        }
        float4 acc;
        acc.x = (a0.x + a1.x) + (a2.x + a3.x);
        acc.y = (a0.y + a1.y) + (a2.y + a3.y);
        acc.z = (a0.z + a1.z) + (a2.z + a3.z);
        acc.w = (a0.w + a1.w) + (a2.w + a3.w);

        const int tgt_tok = rem_tok[b * NR + 52 * k];
        float4 bv = hb[(size_t)tgt_tok * 256 + tid];
        float inv = 1.0f / fmaxf((float)cnt, 1.0f);
        float4 o;
        o.x = bv.x + acc.x * inv; o.y = bv.y + acc.y * inv;
        o.z = bv.z + acc.z * inv; o.w = bv.w + acc.w * inv;
        dst[tid] = o;
    }
}

extern "C" void kernel_launch(void* const* d_in, const int* in_sizes, int n_in,
                              void* d_out, int out_size, void* d_ws, size_t ws_size,
                              hipStream_t stream) {
    const float* attn   = (const float*)d_in[0];
    const float* hidden = (const float*)d_in[1];
    const float* metric = (const float*)d_in[2];
    const float* text   = (const float*)d_in[3];
    float* out = (float*)d_out;

    char* ws = (char*)d_ws;
    size_t off = 0;
    auto alloc = [&](size_t bytes) { void* p = ws + off; off = (off + bytes + 255) & ~(size_t)255; return p; };
    int* dom_idx     = (int*)alloc((size_t)B_ * NSEL * 4);
    int* rem_tok     = (int*)alloc((size_t)B_ * NR * 4);
    int* bucket_toks = (int*)alloc((size_t)B_ * CTX * NMERGE * 4);
    int* bucket_cnt  = (int*)alloc((size_t)B_ * CTX * 4);

    k_score <<<B_, LP, 0, stream>>>(attn, metric, text, dom_idx, rem_tok);
    k_assign<<<B_, NMERGE, 0, stream>>>(metric, rem_tok, bucket_toks, bucket_cnt);
    k_out   <<<B_ * 65, 256, 0, stream>>>(hidden, dom_idx, rem_tok, bucket_toks, bucket_cnt, out);
}

// Round 3
// 59.458 us; speedup vs baseline: 1.7877x; 1.0106x over previous
//
#include <hip/hip_runtime.h>

#define B_   32
#define H_   16
#define L_   577
#define D_   1024
#define CK   64
#define LP   576    // L-1 patches
#define DOM  54
#define NSEL 55     // DOM + CLS
#define NR   522    // LP - DOM
#define CTX  10
#define NMERGE 512  // NR - CTX

// remain-list position for merge index m: p = m + min(m/51,9) + 1
__device__ __forceinline__ int remain_pos(int m) {
    int k = m / 51; if (k > 9) k = 9;
    return m + k + 1;
}

// block-wide sum over 576 threads (9 waves)
__device__ float block_sum576(float v) {
    __shared__ float red[9];
    __shared__ float tot;
    for (int o = 32; o; o >>= 1) v += __shfl_xor(v, o);
    if ((threadIdx.x & 63) == 0) red[threadIdx.x >> 6] = v;
    __syncthreads();
    if (threadIdx.x < 16) {
        float s = (threadIdx.x < 9) ? red[threadIdx.x] : 0.f;
        for (int o = 8; o; o >>= 1) s += __shfl_xor(s, o);
        if (threadIdx.x == 0) tot = s;
    }
    __syncthreads();
    float r = tot;
    __syncthreads();
    return r;
}

// K0 (wide grid): raw per-patch scores Sd and cos — all 256 CUs busy
__global__ __launch_bounds__(256) void k_raw(
    const float* __restrict__ attn, const float* __restrict__ metric,
    const float* __restrict__ text, float* __restrict__ Sd_arr,
    float* __restrict__ cos_arr)
{
    const int t = blockIdx.x * 256 + threadIdx.x;   // t in [0, B_*LP)
    const int b = t / LP, j = t - b * LP;

    float Sd = 0.f;
    {
        size_t base = (size_t)b * H_ * L_ * L_ + (size_t)(1 + j);
        #pragma unroll
        for (int h = 0; h < H_; ++h)
            Sd += attn[base + (size_t)h * L_ * L_];
    }

    const float4* row  = (const float4*)&metric[((size_t)(b * L_ + 1 + j)) * CK];
    const float4* trow = (const float4*)&text[(size_t)b * CK];
    float dot = 0.f, ss = 0.f, ts = 0.f;
    #pragma unroll
    for (int c4 = 0; c4 < CK / 4; ++c4) {
        float4 v = row[c4];
        float4 tv = trow[c4];   // broadcast within batch, L1-hot
        ss  += v.x * v.x + v.y * v.y + v.z * v.z + v.w * v.w;
        ts  += tv.x * tv.x + tv.y * tv.y + tv.z * tv.z + tv.w * tv.w;
        dot += v.x * tv.x + v.y * tv.y + v.z * tv.z + v.w * tv.w;
    }
    float cosv = dot / (sqrtf(ss) + 1e-12f) / (sqrtf(ts) + 1e-12f);

    Sd_arr[t]  = Sd;
    cos_arr[t] = cosv;
}

// K1: z-score + top-54 selection + lists + fused bucket assignment
__global__ __launch_bounds__(576) void k_select(
    const float* __restrict__ Sd_arr, const float* __restrict__ cos_arr,
    const float* __restrict__ metric,
    int* __restrict__ dom_idx, int* __restrict__ rem_tok,
    int* __restrict__ bucket_toks, int* __restrict__ bucket_cnt)
{
    const int b = blockIdx.x;
    const int j = threadIdx.x;       // patch index 0..575, token j+1

    __shared__ float sc[LP];
    __shared__ unsigned long long smask[9];
    __shared__ int   rem_s[NR];
    __shared__ float tg[CTX * CK];
    __shared__ float tinv[CTX];
    __shared__ unsigned long long bmask[8][CTX];

    float Sd   = Sd_arr[b * LP + j];
    float cosv = cos_arr[b * LP + j];

    // z-scores (ddof=1, eps added to std)
    float mS = block_sum576(Sd)   * (1.f / LP);
    float dS = Sd - mS;
    float vS = block_sum576(dS * dS) * (1.f / (LP - 1));
    float mC = block_sum576(cosv) * (1.f / LP);
    float dC = cosv - mC;
    float vC = block_sum576(dC * dC) * (1.f / (LP - 1));

    float score = 0.5f * dS / (sqrtf(vS) + 1e-6f) + 0.5f * dC / (sqrtf(vC) + 1e-6f);
    sc[j] = score;
    __syncthreads();

    // rank with stable tie-break (score desc, index asc) — exact top_k reproduction
    int rank = 0;
    for (int k = 0; k < LP; ++k) {
        float s = sc[k];
        rank += (s > score) || (s == score && k < j);
    }
    bool selj = (rank < DOM);

    // ballot-based stable prefix
    const int w = j >> 6, lane = j & 63;
    unsigned long long m = __ballot(selj);
    if (lane == 0) smask[w] = m;
    __syncthreads();
    int pre = 0;
    for (int ww = 0; ww < w; ++ww) pre += __popcll(smask[ww]);
    pre += __popcll(smask[w] & ((1ull << lane) - 1ull));

    if (j == 0) dom_idx[b * NSEL] = 0;
    if (selj) dom_idx[b * NSEL + 1 + pre] = j + 1;
    else { rem_s[j - pre] = j + 1; rem_tok[b * NR + (j - pre)] = j + 1; }
    __syncthreads();

    // ---- fused assignment phase ----
    // stage 10 raw target rows from metric
    for (int i = j; i < CTX * CK; i += 576) {
        int k = i >> 6, c = i & 63;
        int tok = rem_s[52 * k];
        tg[i] = metric[((size_t)(b * L_ + tok)) * CK + c];
    }
    __syncthreads();
    if (j < CTX) {
        float s = 0.f;
        for (int c = 0; c < CK; ++c) { float t = tg[j * CK + c]; s += t * t; }
        tinv[j] = 1.f / (sqrtf(s) + 1e-12f);
    }
    __syncthreads();

    if (j < NMERGE) {   // waves 0..7 fully active, wave 8 skips (uniform)
        const int p = remain_pos(j);
        const int tok = rem_s[p];
        const float4* mrow = (const float4*)&metric[((size_t)(b * L_ + tok)) * CK];
        float4 r[CK / 4];
        #pragma unroll
        for (int c4 = 0; c4 < CK / 4; ++c4) r[c4] = mrow[c4];

        // argmax_k: merge-row norm dropped (positive scalar, argmax-invariant)
        float best = -1e30f; int bk = 0;
        #pragma unroll
        for (int k = 0; k < CTX; ++k) {
            float d = 0.f;
            #pragma unroll
            for (int c4 = 0; c4 < CK / 4; ++c4) {
                float4 v = r[c4];
                d += v.x * tg[k*CK + c4*4+0] + v.y * tg[k*CK + c4*4+1] +
                     v.z * tg[k*CK + c4*4+2] + v.w * tg[k*CK + c4*4+3];
            }
            d *= tinv[k];
            if (d > best) { best = d; bk = k; }   // strict > : first max (jnp.argmax)
        }

        // stable compaction: pos = #{i < j : assign_i == bk}
        #pragma unroll
        for (int k = 0; k < CTX; ++k) {
            unsigned long long mk = __ballot(bk == k);
            if (lane == 0) bmask[w][k] = mk;
        }
        __syncthreads();
        int pos = 0;
        for (int ww = 0; ww < w; ++ww) pos += __popcll(bmask[ww][bk]);
        pos += __popcll(bmask[w][bk] & ((1ull << lane) - 1ull));
        bucket_toks[((size_t)(b * CTX + bk)) * NMERGE + pos] = tok;

        if (j < CTX) {
            int c = 0;
            #pragma unroll
            for (int ww = 0; ww < 8; ++ww) c += __popcll(bmask[ww][j]);
            bucket_cnt[b * CTX + j] = c;
        }
    } else {
        __syncthreads();   // match barrier inside the if (wave-uniform branch)
    }
}

// K2: gather dominant rows + aggregate contextual rows (ILP x8)
__global__ __launch_bounds__(256) void k_out(
    const float* __restrict__ hidden, const int* __restrict__ dom_idx,
    const int* __restrict__ rem_tok, const int* __restrict__ bucket_toks,
    const int* __restrict__ bucket_cnt, float* __restrict__ out)
{
    const int b = blockIdx.x / 65, r = blockIdx.x % 65;
    const int tid = threadIdx.x;
    float4* dst = (float4*)&out[((size_t)(b * 65 + r)) * D_];

    if (r < NSEL) {
        int tok = dom_idx[b * NSEL + r];
        const float4* src = (const float4*)&hidden[((size_t)(b * L_ + tok)) * D_];
        dst[tid] = src[tid];
    } else {
        const int k = r - NSEL;
        const int cnt = bucket_cnt[b * CTX + k];
        __shared__ int toks[NMERGE];
        for (int i = tid; i < cnt; i += 256)
            toks[i] = bucket_toks[((size_t)(b * CTX + k)) * NMERGE + i];
        __syncthreads();

        const float4* hb = (const float4*)&hidden[((size_t)b * L_) * D_];
        float4 a0 = make_float4(0,0,0,0), a1 = a0, a2 = a0, a3 = a0;
        float4 a4 = a0, a5 = a0, a6 = a0, a7 = a0;
        int i = 0;
        for (; i + 8 <= cnt; i += 8) {
            float4 v0 = hb[(size_t)toks[i+0] * 256 + tid];
            float4 v1 = hb[(size_t)toks[i+1] * 256 + tid];
            float4 v2 = hb[(size_t)toks[i+2] * 256 + tid];
            float4 v3 = hb[(size_t)toks[i+3] * 256 + tid];
            float4 v4 = hb[(size_t)toks[i+4] * 256 + tid];
            float4 v5 = hb[(size_t)toks[i+5] * 256 + tid];
            float4 v6 = hb[(size_t)toks[i+6] * 256 + tid];
            float4 v7 = hb[(size_t)toks[i+7] * 256 + tid];
            a0.x += v0.x; a0.y += v0.y; a0.z += v0.z; a0.w += v0.w;
            a1.x += v1.x; a1.y += v1.y; a1.z += v1.z; a1.w += v1.w;
            a2.x += v2.x; a2.y += v2.y; a2.z += v2.z; a2.w += v2.w;
            a3.x += v3.x; a3.y += v3.y; a3.z += v3.z; a3.w += v3.w;
            a4.x += v4.x; a4.y += v4.y; a4.z += v4.z; a4.w += v4.w;
            a5.x += v5.x; a5.y += v5.y; a5.z += v5.z; a5.w += v5.w;
            a6.x += v6.x; a6.y += v6.y; a6.z += v6.z; a6.w += v6.w;
            a7.x += v7.x; a7.y += v7.y; a7.z += v7.z; a7.w += v7.w;
        }
        for (; i < cnt; ++i) {
            float4 v = hb[(size_t)toks[i] * 256 + tid];
            a0.x += v.x; a0.y += v.y; a0.z += v.z; a0.w += v.w;
        }
        float4 acc;
        acc.x = ((a0.x + a1.x) + (a2.x + a3.x)) + ((a4.x + a5.x) + (a6.x + a7.x));
        acc.y = ((a0.y + a1.y) + (a2.y + a3.y)) + ((a4.y + a5.y) + (a6.y + a7.y));
        acc.z = ((a0.z + a1.z) + (a2.z + a3.z)) + ((a4.z + a5.z) + (a6.z + a7.z));
        acc.w = ((a0.w + a1.w) + (a2.w + a3.w)) + ((a4.w + a5.w) + (a6.w + a7.w));

        const int tgt_tok = rem_tok[b * NR + 52 * k];
        float4 bv = hb[(size_t)tgt_tok * 256 + tid];
        float inv = 1.0f / fmaxf((float)cnt, 1.0f);
        float4 o;
        o.x = bv.x + acc.x * inv; o.y = bv.y + acc.y * inv;
        o.z = bv.z + acc.z * inv; o.w = bv.w + acc.w * inv;
        dst[tid] = o;
    }
}

extern "C" void kernel_launch(void* const* d_in, const int* in_sizes, int n_in,
                              void* d_out, int out_size, void* d_ws, size_t ws_size,
                              hipStream_t stream) {
    const float* attn   = (const float*)d_in[0];
    const float* hidden = (const float*)d_in[1];
    const float* metric = (const float*)d_in[2];
    const float* text   = (const float*)d_in[3];
    float* out = (float*)d_out;

    char* ws = (char*)d_ws;
    size_t off = 0;
    auto alloc = [&](size_t bytes) { void* p = ws + off; off = (off + bytes + 255) & ~(size_t)255; return p; };
    float* Sd_arr      = (float*)alloc((size_t)B_ * LP * 4);
    float* cos_arr     = (float*)alloc((size_t)B_ * LP * 4);
    int*   dom_idx     = (int*)  alloc((size_t)B_ * NSEL * 4);
    int*   rem_tok     = (int*)  alloc((size_t)B_ * NR * 4);
    int*   bucket_toks = (int*)  alloc((size_t)B_ * CTX * NMERGE * 4);
    int*   bucket_cnt  = (int*)  alloc((size_t)B_ * CTX * 4);

    k_raw   <<<(B_ * LP) / 256, 256, 0, stream>>>(attn, metric, text, Sd_arr, cos_arr);
    k_select<<<B_, LP, 0, stream>>>(Sd_arr, cos_arr, metric, dom_idx, rem_tok,
                                    bucket_toks, bucket_cnt);
    k_out   <<<B_ * 65, 256, 0, stream>>>(hidden, dom_idx, rem_tok, bucket_toks,
                                          bucket_cnt, out);
}